// Round 2
// baseline (48.389 us; speedup 1.0000x reference)
//
#include <hip/hip_runtime.h>

#define DIM   1024
#define BATCH 8
#define SEQ   2048
#define CHUNKS 64
#define ROWS  (SEQ / CHUNKS)   // 32 rows per partial-sum block
#define LN_EPS 1e-5f

typedef float v4 __attribute__((ext_vector_type(4)));

// ---------------------------------------------------------------------------
// Stage 1a: partial column sums of x over s, float4 path.
// grid (CHUNKS, BATCH), block 256. Thread t owns columns [4t, 4t+4).
// partial[c][b][e] = sum_{s in chunk c} x[b,s,e]
// ---------------------------------------------------------------------------
__global__ __launch_bounds__(256) void k_partial_colsum(
    const float* __restrict__ x, float* __restrict__ partial) {
  int c = blockIdx.x;
  int b = blockIdx.y;
  int t = threadIdx.x;
  const v4* base =
      (const v4*)(x + ((size_t)b * SEQ + (size_t)c * ROWS) * DIM) + t;
  v4 acc = {0.f, 0.f, 0.f, 0.f};
#pragma unroll 8
  for (int s = 0; s < ROWS; ++s) acc += base[(size_t)s * (DIM / 4)];
  ((v4*)partial)[((size_t)c * BATCH + b) * (DIM / 4) + t] = acc;
}

// Stage 1b: finish column sum. grid (BATCH*DIM/4/256 = 8), block 256.
__global__ __launch_bounds__(256) void k_finish_colsum(
    const float* __restrict__ partial, float* __restrict__ xsum) {
  int i4 = blockIdx.x * 256 + threadIdx.x;  // over BATCH*DIM/4
  const v4* p = (const v4*)partial;
  v4 acc = {0.f, 0.f, 0.f, 0.f};
#pragma unroll 8
  for (int c = 0; c < CHUNKS; ++c) acc += p[(size_t)c * BATCH * (DIM / 4) + i4];
  ((v4*)xsum)[i4] = acc;
}

// ---------------------------------------------------------------------------
// Stage 2: batched GEMV, one wave per output element, float4 dot.
// out[b,d] = sum_e in[b,e] * W[d,e] (+ bias[d])
// grid (BATCH*DIM/4), block 256 (4 waves).
// ---------------------------------------------------------------------------
__global__ __launch_bounds__(256) void k_gemv(
    const float* __restrict__ vin, const float* __restrict__ W,
    const float* __restrict__ bias, float* __restrict__ vout) {
  int wave = threadIdx.x >> 6;
  int lane = threadIdx.x & 63;
  int o = blockIdx.x * 4 + wave;          // 0 .. BATCH*DIM-1
  int b = o >> 10;                        // DIM = 1024
  int d = o & (DIM - 1);
  const v4* in4 = (const v4*)(vin + (size_t)b * DIM);
  const v4* w4  = (const v4*)(W + (size_t)d * DIM);
  float acc = 0.f;
#pragma unroll
  for (int j = 0; j < 4; ++j) {
    v4 w = w4[lane + 64 * j];
    v4 i = in4[lane + 64 * j];
    acc += w.x * i.x + w.y * i.y + w.z * i.z + w.w * i.w;
  }
#pragma unroll
  for (int off = 32; off; off >>= 1) acc += __shfl_xor(acc, off, 64);
  if (lane == 0) {
    float r = acc;
    if (bias) r += bias[d];
    vout[o] = r;
  }
}

// ---------------------------------------------------------------------------
// Stage 3: out[b,s,:] = LayerNorm(x[b,s,:] + z[b,:]) * gamma + beta
// Wave-per-row: no LDS, no __syncthreads. grid (B*S/4), block 256 (4 waves).
// Each lane holds 16 elements (4 x float4). Non-temporal store for out.
// ---------------------------------------------------------------------------
__global__ __launch_bounds__(256) void k_residual_ln(
    const float* __restrict__ x, const float* __restrict__ z,
    const float* __restrict__ gamma, const float* __restrict__ beta,
    float* __restrict__ out) {
  int wave = threadIdx.x >> 6;
  int lane = threadIdx.x & 63;
  int row = blockIdx.x * 4 + wave;   // 0 .. B*S-1
  int b   = row >> 11;               // SEQ = 2048

  const v4* xr = (const v4*)(x + (size_t)row * DIM);
  const v4* zr = (const v4*)(z + (size_t)b * DIM);

  v4 h[4];
  float sum = 0.f, ss = 0.f;
#pragma unroll
  for (int j = 0; j < 4; ++j) {
    v4 xv = xr[lane + 64 * j];
    v4 zv = zr[lane + 64 * j];
    v4 hv = xv + zv;
    h[j] = hv;
    sum += hv.x + hv.y + hv.z + hv.w;
    ss  += hv.x * hv.x + hv.y * hv.y + hv.z * hv.z + hv.w * hv.w;
  }
#pragma unroll
  for (int off = 32; off; off >>= 1) {
    sum += __shfl_xor(sum, off, 64);
    ss  += __shfl_xor(ss,  off, 64);
  }

  const float inv = 1.0f / (float)DIM;
  float mu = sum * inv;
  float rs = rsqrtf(ss * inv - mu * mu + LN_EPS);

  v4* outr = (v4*)out + (size_t)row * (DIM / 4);
#pragma unroll
  for (int j = 0; j < 4; ++j) {
    v4 g  = ((const v4*)gamma)[lane + 64 * j];
    v4 be = ((const v4*)beta)[lane + 64 * j];
    v4 o = (h[j] - mu) * rs * g + be;
    __builtin_nontemporal_store(o, &outr[lane + 64 * j]);
  }
}

extern "C" void kernel_launch(void* const* d_in, const int* in_sizes, int n_in,
                              void* d_out, int out_size, void* d_ws, size_t ws_size,
                              hipStream_t stream) {
  const float* x     = (const float*)d_in[0];   // [B, S, D]
  const float* w_qkv = (const float*)d_in[1];   // [3D, D]
  const float* w_fc  = (const float*)d_in[2];   // [D, D]
  const float* b_fc  = (const float*)d_in[3];   // [D]
  const float* gamma = (const float*)d_in[4];   // [D]
  const float* beta  = (const float*)d_in[5];   // [D]
  float* out = (float*)d_out;

  // workspace layout (floats)
  float* ws      = (float*)d_ws;
  float* partial = ws;                                        // CHUNKS*B*D
  float* xsum    = partial + (size_t)CHUNKS * BATCH * DIM;    // B*D
  float* vsum    = xsum + (size_t)BATCH * DIM;                // B*D
  float* z       = vsum + (size_t)BATCH * DIM;                // B*D

  const float* w_v = w_qkv + (size_t)2 * DIM * DIM;  // rows [2D, 3D) of w_qkv

  // 1) xsum[b,e] = sum_s x[b,s,e]   (fills L3 with x)
  hipLaunchKernelGGL(k_partial_colsum, dim3(CHUNKS, BATCH), dim3(256), 0,
                     stream, x, partial);
  hipLaunchKernelGGL(k_finish_colsum, dim3(BATCH * DIM / 4 / 256), dim3(256),
                     0, stream, partial, xsum);

  // 2) vsum = xsum @ Wv^T ; z = vsum @ Wfc^T + b_fc
  hipLaunchKernelGGL(k_gemv, dim3(BATCH * DIM / 4), dim3(256), 0, stream,
                     xsum, w_v, (const float*)nullptr, vsum);
  hipLaunchKernelGGL(k_gemv, dim3(BATCH * DIM / 4), dim3(256), 0, stream,
                     vsum, w_fc, b_fc, z);

  // 3) out = LN(x + z) * gamma + beta   (x re-read should hit L3; out is NT)
  hipLaunchKernelGGL(k_residual_ln, dim3(BATCH * SEQ / 4), dim3(256), 0,
                     stream, x, z, gamma, beta, out);
}